// Round 3
// baseline (87.521 us; speedup 1.0000x reference)
//
#include <hip/hip_runtime.h>
#include <math.h>

#define JN 9
#define BLK 128

__device__ __forceinline__ void mat3_vec(const float* R, const float* x, float* y) {
    y[0] = R[0]*x[0] + R[1]*x[1] + R[2]*x[2];
    y[1] = R[3]*x[0] + R[4]*x[1] + R[5]*x[2];
    y[2] = R[6]*x[0] + R[7]*x[1] + R[8]*x[2];
}

__device__ __forceinline__ void cross3(const float* a, const float* b, float* o) {
    o[0] = a[1]*b[2] - a[2]*b[1];
    o[1] = a[2]*b[0] - a[0]*b[2];
    o[2] = a[0]*b[1] - a[1]*b[0];
}

// y = Adjoint(T) x for T=(R,p):  y_w = R x_w ;  y_v = p x (R x_w) + R x_v
__device__ __forceinline__ void adj_apply(const float* R, const float* p,
                                          const float* x, float* y) {
    float t[3], cr[3], rv[3];
    mat3_vec(R, x, t);
    cross3(p, t, cr);
    mat3_vec(R, x + 3, rv);
    y[0] = t[0]; y[1] = t[1]; y[2] = t[2];
    y[3] = cr[0] + rv[0]; y[4] = cr[1] + rv[1]; y[5] = cr[2] + rv[2];
}

__device__ __forceinline__ void adj_apply_inplace(const float* R, const float* p, float* x) {
    float y[6];
    adj_apply(R, p, x, y);
#pragma unroll
    for (int k = 0; k < 6; ++k) x[k] = y[k];
}

__global__ void __launch_bounds__(BLK)
id_kernel(const float* __restrict__ q, const float* __restrict__ dq,
          const float* __restrict__ ddq, const float* __restrict__ gvec,
          const float* __restrict__ Ftip, const float* __restrict__ Alist,
          const float* __restrict__ Mlist, const float* __restrict__ Glist,
          float* __restrict__ out, int B)
{
    __shared__ float sA[JN][6];
    __shared__ float sG[JN][36];
    __shared__ float sR[JN + 1][9];   // rotation of Minv_j (= R_j^T)
    __shared__ float sP[JN + 1][3];   // translation of Minv_j (= -R_j^T p_j)

    const int tid = threadIdx.x;
    for (int i = tid; i < JN * 6;  i += BLK) (&sA[0][0])[i] = Alist[i];
    for (int i = tid; i < JN * 36; i += BLK) (&sG[0][0])[i] = Glist[i];
    if (tid < JN + 1) {
        const float* M = Mlist + tid * 16;
        float Rt[9] = { M[0], M[4], M[8],
                        M[1], M[5], M[9],
                        M[2], M[6], M[10] };
#pragma unroll
        for (int r = 0; r < 9; ++r) sR[tid][r] = Rt[r];
        float p0 = M[3], p1 = M[7], p2 = M[11];
        sP[tid][0] = -(Rt[0]*p0 + Rt[1]*p1 + Rt[2]*p2);
        sP[tid][1] = -(Rt[3]*p0 + Rt[4]*p1 + Rt[5]*p2);
        sP[tid][2] = -(Rt[6]*p0 + Rt[7]*p1 + Rt[8]*p2);
    }
    __syncthreads();

    const int b = blockIdx.x * BLK + tid;
    if (b >= B) return;

    float v[6] = {0.f, 0.f, 0.f, 0.f, 0.f, 0.f};
    float a[6] = {0.f, 0.f, 0.f, -gvec[0], -gvec[1], -gvec[2]};
    float c[JN][6];     // pushed-forward screw axes (registers, static-indexed)
    float tau[JN];
#pragma unroll
    for (int i = 0; i < JN; ++i) tau[i] = 0.f;

#pragma unroll
    for (int j = 0; j < JN; ++j) {
        const float qj   = q[b * JN + j];
        const float dqj  = dq[b * JN + j];
        const float ddqj = ddq[b * JN + j];
        float Aj[6];
#pragma unroll
        for (int k = 0; k < 6; ++k) Aj[k] = sA[j][k];

        // ---- matrix_exp6(-Aj * qj) ----
        const float w0 = -Aj[0] * qj, w1 = -Aj[1] * qj, w2 = -Aj[2] * qj;
        const float l0 = -Aj[3] * qj, l1 = -Aj[4] * qj, l2 = -Aj[5] * qj;
        const float th = sqrtf(w0*w0 + w1*w1 + w2*w2);
        const bool near = th < 1e-6f;
        const float safe = near ? 1.f : th;
        const float inv = __builtin_amdgcn_rcpf(safe);
        const float x = w0 * inv, y = w1 * inv, z = w2 * inv;
        const float st = __sinf(th), ct = __cosf(th);
        const float s2 = 1.f - ct;
        const float a00 = -(z*z + y*y), a11 = -(z*z + x*x), a22 = -(y*y + x*x);
        const float a01 = x*y, a02 = x*z, a12 = y*z;
        float R[9];
        R[0] = 1.f + s2*a00;     R[1] = -st*z + s2*a01;  R[2] =  st*y + s2*a02;
        R[3] =  st*z + s2*a01;   R[4] = 1.f + s2*a11;    R[5] = -st*x + s2*a12;
        R[6] = -st*y + s2*a02;   R[7] =  st*x + s2*a12;  R[8] = 1.f + s2*a22;
        if (near) {
            R[0]=1.f; R[1]=0.f; R[2]=0.f;
            R[3]=0.f; R[4]=1.f; R[5]=0.f;
            R[6]=0.f; R[7]=0.f; R[8]=1.f;
        }
        const float g3 = th - st;
        const float u0 = l0 * inv, u1 = l1 * inv, u2 = l2 * inv;
        float p0 = th*u0 + s2*(-z*u1 + y*u2) + g3*(a00*u0 + a01*u1 + a02*u2);
        float p1 = th*u1 + s2*( z*u0 - x*u2) + g3*(a01*u0 + a11*u1 + a12*u2);
        float p2 = th*u2 + s2*(-y*u0 + x*u1) + g3*(a02*u0 + a12*u1 + a22*u2);
        if (near) { p0 = l0; p1 = l1; p2 = l2; }

        // ---- T = exp6(-A q) @ Minv_j :  TR = R*sR[j], Tp = R*sP[j] + p ----
        float TR[9], Tp[3];
        {
            const float* Mr = sR[j];
#pragma unroll
            for (int r = 0; r < 3; ++r) {
#pragma unroll
                for (int cc = 0; cc < 3; ++cc) {
                    TR[r*3+cc] = R[r*3+0]*Mr[0*3+cc] + R[r*3+1]*Mr[1*3+cc] + R[r*3+2]*Mr[2*3+cc];
                }
            }
            const float* Mp = sP[j];
            Tp[0] = R[0]*Mp[0] + R[1]*Mp[1] + R[2]*Mp[2] + p0;
            Tp[1] = R[3]*Mp[0] + R[4]*Mp[1] + R[5]*Mp[2] + p1;
            Tp[2] = R[6]*Mp[0] + R[7]*Mp[1] + R[8]*Mp[2] + p2;
        }

        // ---- push forward all previous screw axes: c_i <- Ad(T_j) c_i ----
#pragma unroll
        for (int i = 0; i < j; ++i) adj_apply_inplace(TR, Tp, c[i]);

        // ---- v, a update ----
        float vn[6], an[6];
        adj_apply(TR, Tp, v, vn);
#pragma unroll
        for (int k = 0; k < 6; ++k) vn[k] += Aj[k] * dqj;
        adj_apply(TR, Tp, a, an);
        {
            float t0[3], t1[3], t2[3];
            cross3(vn, Aj, t0);        // w(vn) x Aw
            cross3(vn + 3, Aj, t1);    // v(vn) x Aw
            cross3(vn, Aj + 3, t2);    // w(vn) x Av
            an[0] += t0[0]*dqj + Aj[0]*ddqj;
            an[1] += t0[1]*dqj + Aj[1]*ddqj;
            an[2] += t0[2]*dqj + Aj[2]*ddqj;
            an[3] += (t1[0]+t2[0])*dqj + Aj[3]*ddqj;
            an[4] += (t1[1]+t2[1])*dqj + Aj[4]*ddqj;
            an[5] += (t1[2]+t2[2])*dqj + Aj[5]*ddqj;
        }
#pragma unroll
        for (int k = 0; k < 6; ++k) { v[k] = vn[k]; a[k] = an[k]; }

        // ---- W_j = G a - ad(v)^T (G v) ----
        float Gv[6], Ga[6];
        {
            const float* Gm = sG[j];
#pragma unroll
            for (int r = 0; r < 6; ++r) {
                float sv = 0.f, sa = 0.f;
#pragma unroll
                for (int kk = 0; kk < 6; ++kk) {
                    sv += Gm[r*6+kk] * v[kk];
                    sa += Gm[r*6+kk] * a[kk];
                }
                Gv[r] = sv; Ga[r] = sa;
            }
        }
        float cw[3], cv[3], cb[3];
        cross3(v, Gv, cw);          // w x (Gv)_w
        cross3(v + 3, Gv + 3, cv);  // vv x (Gv)_v
        cross3(v, Gv + 3, cb);      // w x (Gv)_v
        const float W[6] = { Ga[0]+cw[0]+cv[0], Ga[1]+cw[1]+cv[1], Ga[2]+cw[2]+cv[2],
                             Ga[3]+cb[0],       Ga[4]+cb[1],       Ga[5]+cb[2] };

        // ---- c_j = A_j ; tau_i += c_i . W_j for i <= j ----
#pragma unroll
        for (int k = 0; k < 6; ++k) c[j][k] = Aj[k];
#pragma unroll
        for (int i = 0; i <= j; ++i) {
            float d = 0.f;
#pragma unroll
            for (int k = 0; k < 6; ++k) d += c[i][k] * W[k];
            tau[i] += d;
        }
    }

    // ---- final: c_i <- Ad(Minv[JN]) c_i ; tau_i += c_i . Ftip ----
    float Ft[6];
#pragma unroll
    for (int k = 0; k < 6; ++k) Ft[k] = Ftip[b * 6 + k];
#pragma unroll
    for (int i = 0; i < JN; ++i) {
        adj_apply_inplace(sR[JN], sP[JN], c[i]);
        float d = 0.f;
#pragma unroll
        for (int k = 0; k < 6; ++k) d += c[i][k] * Ft[k];
        tau[i] += d;
        out[b * JN + i] = tau[i];
    }
}

extern "C" void kernel_launch(void* const* d_in, const int* in_sizes, int n_in,
                              void* d_out, int out_size, void* d_ws, size_t ws_size,
                              hipStream_t stream) {
    const float* q     = (const float*)d_in[0];
    const float* dq    = (const float*)d_in[1];
    const float* ddq   = (const float*)d_in[2];
    const float* g     = (const float*)d_in[3];
    const float* Ftip  = (const float*)d_in[4];
    const float* Alist = (const float*)d_in[5];
    const float* Mlist = (const float*)d_in[6];
    const float* Glist = (const float*)d_in[7];
    float* out = (float*)d_out;

    const int B = in_sizes[0] / JN;
    const int grid = (B + BLK - 1) / BLK;
    hipLaunchKernelGGL(id_kernel, dim3(grid), dim3(BLK), 0, stream,
                       q, dq, ddq, g, Ftip, Alist, Mlist, Glist, out, B);
}

// Round 4
// 28.424 us; speedup vs baseline: 3.0791x; 3.0791x over previous
//
#include <hip/hip_runtime.h>
#include <math.h>

#define JN 9
#define BLK 128

__device__ __forceinline__ void mat3_vec(const float* R, const float* x, float* y) {
    y[0] = R[0]*x[0] + R[1]*x[1] + R[2]*x[2];
    y[1] = R[3]*x[0] + R[4]*x[1] + R[5]*x[2];
    y[2] = R[6]*x[0] + R[7]*x[1] + R[8]*x[2];
}

// y = R^T x
__device__ __forceinline__ void mat3T_vec(const float* R, const float* x, float* y) {
    y[0] = R[0]*x[0] + R[3]*x[1] + R[6]*x[2];
    y[1] = R[1]*x[0] + R[4]*x[1] + R[7]*x[2];
    y[2] = R[2]*x[0] + R[5]*x[1] + R[8]*x[2];
}

__device__ __forceinline__ void cross3(const float* a, const float* b, float* o) {
    o[0] = a[1]*b[2] - a[2]*b[1];
    o[1] = a[2]*b[0] - a[0]*b[2];
    o[2] = a[0]*b[1] - a[1]*b[0];
}

// y = Adjoint(T) x for T=(R,p):  y_w = R x_w ;  y_v = p x (R x_w) + R x_v
__device__ __forceinline__ void adj_apply(const float* R, const float* p,
                                          const float* x, float* y) {
    float t[3], cr[3], rv[3];
    mat3_vec(R, x, t);
    cross3(p, t, cr);
    mat3_vec(R, x + 3, rv);
    y[0] = t[0]; y[1] = t[1]; y[2] = t[2];
    y[3] = cr[0] + rv[0]; y[4] = cr[1] + rv[1]; y[5] = cr[2] + rv[2];
}

// y = Adjoint(T)^T x for T=(R,p): y_w = R^T (x_w - p x x_v) ; y_v = R^T x_v
__device__ __forceinline__ void adjT_apply(const float* R, const float* p,
                                           const float* x, float* y) {
    float cr[3], t[3];
    cross3(p, x + 3, cr);
    t[0] = x[0] - cr[0]; t[1] = x[1] - cr[1]; t[2] = x[2] - cr[2];
    mat3T_vec(R, t, y);
    mat3T_vec(R, x + 3, y + 3);
}

__global__ void __launch_bounds__(BLK)
id_kernel(const float* __restrict__ q, const float* __restrict__ dq,
          const float* __restrict__ ddq, const float* __restrict__ gvec,
          const float* __restrict__ Ftip, const float* __restrict__ Alist,
          const float* __restrict__ Mlist, const float* __restrict__ Glist,
          float* __restrict__ out, int B)
{
    __shared__ float sA[JN][6];
    __shared__ float sG[JN][36];
    __shared__ float sR[JN + 1][9];     // rotation of Minv_j (= R_j^T)
    __shared__ float sP[JN + 1][3];     // translation of Minv_j (= -R_j^T p_j)
    __shared__ float sB[JN * 6][BLK];   // base-frame screw axes B_i (write once)
    __shared__ float sSig[JN][BLK];     // sigma_i = B_i . U_{i-1}

    const int tid = threadIdx.x;
    for (int i = tid; i < JN * 6;  i += BLK) (&sA[0][0])[i] = Alist[i];
    for (int i = tid; i < JN * 36; i += BLK) (&sG[0][0])[i] = Glist[i];
    if (tid < JN + 1) {
        const float* M = Mlist + tid * 16;
        float Rt[9] = { M[0], M[4], M[8],
                        M[1], M[5], M[9],
                        M[2], M[6], M[10] };
#pragma unroll
        for (int r = 0; r < 9; ++r) sR[tid][r] = Rt[r];
        float p0 = M[3], p1 = M[7], p2 = M[11];
        sP[tid][0] = -(Rt[0]*p0 + Rt[1]*p1 + Rt[2]*p2);
        sP[tid][1] = -(Rt[3]*p0 + Rt[4]*p1 + Rt[5]*p2);
        sP[tid][2] = -(Rt[6]*p0 + Rt[7]*p1 + Rt[8]*p2);
    }
    __syncthreads();

    const int b = blockIdx.x * BLK + tid;
    if (b >= B) return;

    // cumulative X_j = T_j ... T_0 ; base-frame twist/accel ; prefix sum U
    float XR[9] = {1.f,0.f,0.f, 0.f,1.f,0.f, 0.f,0.f,1.f};
    float Xp[3] = {0.f, 0.f, 0.f};
    float bv[6] = {0.f, 0.f, 0.f, 0.f, 0.f, 0.f};
    float ba[6] = {0.f, 0.f, 0.f, -gvec[0], -gvec[1], -gvec[2]};
    float U[6]  = {0.f, 0.f, 0.f, 0.f, 0.f, 0.f};

#pragma unroll 1
    for (int j = 0; j < JN; ++j) {
        const float qj   = q[b * JN + j];
        const float dqj  = dq[b * JN + j];
        const float ddqj = ddq[b * JN + j];
        float Aj[6];
#pragma unroll
        for (int k = 0; k < 6; ++k) Aj[k] = sA[j][k];

        // ---- matrix_exp6(-Aj * qj) ----
        const float w0 = -Aj[0] * qj, w1 = -Aj[1] * qj, w2 = -Aj[2] * qj;
        const float l0 = -Aj[3] * qj, l1 = -Aj[4] * qj, l2 = -Aj[5] * qj;
        const float th = sqrtf(w0*w0 + w1*w1 + w2*w2);
        const bool near = th < 1e-6f;
        const float safe = near ? 1.f : th;
        const float inv = __builtin_amdgcn_rcpf(safe);
        const float x = w0 * inv, y = w1 * inv, z = w2 * inv;
        const float st = __sinf(th), ct = __cosf(th);
        const float s2 = 1.f - ct;
        const float a00 = -(z*z + y*y), a11 = -(z*z + x*x), a22 = -(y*y + x*x);
        const float a01 = x*y, a02 = x*z, a12 = y*z;
        float R[9];
        R[0] = 1.f + s2*a00;     R[1] = -st*z + s2*a01;  R[2] =  st*y + s2*a02;
        R[3] =  st*z + s2*a01;   R[4] = 1.f + s2*a11;    R[5] = -st*x + s2*a12;
        R[6] = -st*y + s2*a02;   R[7] =  st*x + s2*a12;  R[8] = 1.f + s2*a22;
        if (near) {
            R[0]=1.f; R[1]=0.f; R[2]=0.f;
            R[3]=0.f; R[4]=1.f; R[5]=0.f;
            R[6]=0.f; R[7]=0.f; R[8]=1.f;
        }
        const float g3 = th - st;
        const float u0 = l0 * inv, u1 = l1 * inv, u2 = l2 * inv;
        float p0 = th*u0 + s2*(-z*u1 + y*u2) + g3*(a00*u0 + a01*u1 + a02*u2);
        float p1 = th*u1 + s2*( z*u0 - x*u2) + g3*(a01*u0 + a11*u1 + a12*u2);
        float p2 = th*u2 + s2*(-y*u0 + x*u1) + g3*(a02*u0 + a12*u1 + a22*u2);
        if (near) { p0 = l0; p1 = l1; p2 = l2; }

        // ---- T = exp6(-A q) @ Minv_j :  TR = R*sR[j], Tp = R*sP[j] + p ----
        float TR[9], Tp[3];
        {
            const float* Mr = sR[j];
#pragma unroll
            for (int r = 0; r < 3; ++r) {
#pragma unroll
                for (int cc = 0; cc < 3; ++cc) {
                    TR[r*3+cc] = R[r*3+0]*Mr[0*3+cc] + R[r*3+1]*Mr[1*3+cc] + R[r*3+2]*Mr[2*3+cc];
                }
            }
            const float* Mp = sP[j];
            Tp[0] = R[0]*Mp[0] + R[1]*Mp[1] + R[2]*Mp[2] + p0;
            Tp[1] = R[3]*Mp[0] + R[4]*Mp[1] + R[5]*Mp[2] + p1;
            Tp[2] = R[6]*Mp[0] + R[7]*Mp[1] + R[8]*Mp[2] + p2;
        }

        // ---- X_j = T_j @ X_{j-1} ----
        {
            float nR[9], np[3];
#pragma unroll
            for (int r = 0; r < 3; ++r) {
#pragma unroll
                for (int cc = 0; cc < 3; ++cc) {
                    nR[r*3+cc] = TR[r*3+0]*XR[0*3+cc] + TR[r*3+1]*XR[1*3+cc] + TR[r*3+2]*XR[2*3+cc];
                }
            }
            mat3_vec(TR, Xp, np);
#pragma unroll
            for (int r = 0; r < 9; ++r) XR[r] = nR[r];
            Xp[0] = np[0] + Tp[0]; Xp[1] = np[1] + Tp[1]; Xp[2] = np[2] + Tp[2];
        }

        // ---- B_j = Ad(X_j^{-1}) A_j ;  X^{-1} = (XR^T, -XR^T Xp) ----
        float Bv[6];
        {
            float ip[3];
            mat3T_vec(XR, Xp, ip);
            ip[0] = -ip[0]; ip[1] = -ip[1]; ip[2] = -ip[2];
            float tw[3], tv[3], cr[3];
            mat3T_vec(XR, Aj, tw);
            mat3T_vec(XR, Aj + 3, tv);
            cross3(ip, tw, cr);
            Bv[0] = tw[0]; Bv[1] = tw[1]; Bv[2] = tw[2];
            Bv[3] = cr[0] + tv[0]; Bv[4] = cr[1] + tv[1]; Bv[5] = cr[2] + tv[2];
        }

        // ---- sigma_j = B_j . U_{j-1} (before U update) ----
        float sig = Bv[0]*U[0] + Bv[1]*U[1] + Bv[2]*U[2]
                  + Bv[3]*U[3] + Bv[4]*U[4] + Bv[5]*U[5];

        // ---- base-frame twist/accel updates ----
#pragma unroll
        for (int k = 0; k < 6; ++k) bv[k] += Bv[k] * dqj;
        {
            float t0[3], t1[3], t2[3];
            cross3(bv, Bv, t0);        // w(bv) x B_w
            cross3(bv + 3, Bv, t1);    // v(bv) x B_w
            cross3(bv, Bv + 3, t2);    // w(bv) x B_v
            ba[0] += t0[0]*dqj + Bv[0]*ddqj;
            ba[1] += t0[1]*dqj + Bv[1]*ddqj;
            ba[2] += t0[2]*dqj + Bv[2]*ddqj;
            ba[3] += (t1[0]+t2[0])*dqj + Bv[3]*ddqj;
            ba[4] += (t1[1]+t2[1])*dqj + Bv[4]*ddqj;
            ba[5] += (t1[2]+t2[2])*dqj + Bv[5]*ddqj;
        }

        // ---- link-frame v, a ----
        float vl[6], al[6];
        adj_apply(XR, Xp, bv, vl);
        adj_apply(XR, Xp, ba, al);

        // ---- W_j = G al - ad(vl)^T (G vl) ----
        float Gv[6], Ga[6];
        {
            const float* Gm = sG[j];
#pragma unroll
            for (int r = 0; r < 6; ++r) {
                float sv = 0.f, sa = 0.f;
#pragma unroll
                for (int kk = 0; kk < 6; ++kk) {
                    sv += Gm[r*6+kk] * vl[kk];
                    sa += Gm[r*6+kk] * al[kk];
                }
                Gv[r] = sv; Ga[r] = sa;
            }
        }
        float W[6];
        {
            float cw[3], cv[3], cb[3];
            cross3(vl, Gv, cw);          // w x (Gv)_w
            cross3(vl + 3, Gv + 3, cv);  // vv x (Gv)_v
            cross3(vl, Gv + 3, cb);      // w x (Gv)_v
            W[0] = Ga[0]+cw[0]+cv[0]; W[1] = Ga[1]+cw[1]+cv[1]; W[2] = Ga[2]+cw[2]+cv[2];
            W[3] = Ga[3]+cb[0];       W[4] = Ga[4]+cb[1];       W[5] = Ga[5]+cb[2];
        }

        // ---- S_j = Ad(X_j)^T W_j ; U += S_j ----
        {
            float S[6];
            adjT_apply(XR, Xp, W, S);
#pragma unroll
            for (int k = 0; k < 6; ++k) U[k] += S[k];
        }

        // ---- stash B_j, sigma_j (write-once, read in epilogue) ----
#pragma unroll
        for (int k = 0; k < 6; ++k) sB[j * 6 + k][tid] = Bv[k];
        sSig[j][tid] = sig;
    }

    // ---- X_9 = Minv[9] @ X_8 ; Z = Ad(X_9)^T Ftip ; E = U + Z ----
    float E[6];
    {
        float R9[9], p9[3];
        const float* Mr = sR[JN];
        const float* Mp = sP[JN];
#pragma unroll
        for (int r = 0; r < 3; ++r) {
#pragma unroll
            for (int cc = 0; cc < 3; ++cc) {
                R9[r*3+cc] = Mr[r*3+0]*XR[0*3+cc] + Mr[r*3+1]*XR[1*3+cc] + Mr[r*3+2]*XR[2*3+cc];
            }
        }
        mat3_vec(Mr, Xp, p9);
        p9[0] += Mp[0]; p9[1] += Mp[1]; p9[2] += Mp[2];
        float Ft[6];
#pragma unroll
        for (int k = 0; k < 6; ++k) Ft[k] = Ftip[b * 6 + k];
        float Z[6];
        adjT_apply(R9, p9, Ft, Z);
#pragma unroll
        for (int k = 0; k < 6; ++k) E[k] = U[k] + Z[k];
    }

    // ---- tau_i = B_i . E - sigma_i ----
#pragma unroll
    for (int i = 0; i < JN; ++i) {
        float d = -sSig[i][tid];
#pragma unroll
        for (int k = 0; k < 6; ++k) d += sB[i * 6 + k][tid] * E[k];
        out[b * JN + i] = d;
    }
}

extern "C" void kernel_launch(void* const* d_in, const int* in_sizes, int n_in,
                              void* d_out, int out_size, void* d_ws, size_t ws_size,
                              hipStream_t stream) {
    const float* q     = (const float*)d_in[0];
    const float* dq    = (const float*)d_in[1];
    const float* ddq   = (const float*)d_in[2];
    const float* g     = (const float*)d_in[3];
    const float* Ftip  = (const float*)d_in[4];
    const float* Alist = (const float*)d_in[5];
    const float* Mlist = (const float*)d_in[6];
    const float* Glist = (const float*)d_in[7];
    float* out = (float*)d_out;

    const int B = in_sizes[0] / JN;
    const int grid = (B + BLK - 1) / BLK;
    hipLaunchKernelGGL(id_kernel, dim3(grid), dim3(BLK), 0, stream,
                       q, dq, ddq, g, Ftip, Alist, Mlist, Glist, out, B);
}

// Round 5
// 26.880 us; speedup vs baseline: 3.2559x; 1.0574x over previous
//
#include <hip/hip_runtime.h>
#include <math.h>

#define JN 9
#define BLK 128

__device__ __forceinline__ void mat3_vec(const float* R, const float* x, float* y) {
    y[0] = R[0]*x[0] + R[1]*x[1] + R[2]*x[2];
    y[1] = R[3]*x[0] + R[4]*x[1] + R[5]*x[2];
    y[2] = R[6]*x[0] + R[7]*x[1] + R[8]*x[2];
}

// y = R^T x
__device__ __forceinline__ void mat3T_vec(const float* R, const float* x, float* y) {
    y[0] = R[0]*x[0] + R[3]*x[1] + R[6]*x[2];
    y[1] = R[1]*x[0] + R[4]*x[1] + R[7]*x[2];
    y[2] = R[2]*x[0] + R[5]*x[1] + R[8]*x[2];
}

__device__ __forceinline__ void cross3(const float* a, const float* b, float* o) {
    o[0] = a[1]*b[2] - a[2]*b[1];
    o[1] = a[2]*b[0] - a[0]*b[2];
    o[2] = a[0]*b[1] - a[1]*b[0];
}

// y = Adjoint(T) x for T=(R,p):  y_w = R x_w ;  y_v = p x (R x_w) + R x_v
__device__ __forceinline__ void adj_apply(const float* R, const float* p,
                                          const float* x, float* y) {
    float t[3], cr[3], rv[3];
    mat3_vec(R, x, t);
    cross3(p, t, cr);
    mat3_vec(R, x + 3, rv);
    y[0] = t[0]; y[1] = t[1]; y[2] = t[2];
    y[3] = cr[0] + rv[0]; y[4] = cr[1] + rv[1]; y[5] = cr[2] + rv[2];
}

// y = Adjoint(T)^T x for T=(R,p): y_w = R^T (x_w - p x x_v) ; y_v = R^T x_v
__device__ __forceinline__ void adjT_apply(const float* R, const float* p,
                                           const float* x, float* y) {
    float cr[3], t[3];
    cross3(p, x + 3, cr);
    t[0] = x[0] - cr[0]; t[1] = x[1] - cr[1]; t[2] = x[2] - cr[2];
    mat3T_vec(R, t, y);
    mat3T_vec(R, x + 3, y + 3);
}

__global__ void __launch_bounds__(BLK)
id_kernel(const float* __restrict__ q, const float* __restrict__ dq,
          const float* __restrict__ ddq, const float* __restrict__ gvec,
          const float* __restrict__ Ftip, const float* __restrict__ Alist,
          const float* __restrict__ Mlist, const float* __restrict__ Glist,
          float* __restrict__ out, int B)
{
    __shared__ float sB[JN * 6][BLK];   // base-frame screw axes B_i (write once)
    __shared__ float sSig[JN][BLK];     // sigma_i = B_i . U_{i-1}

    const int tid = threadIdx.x;
    const int b = blockIdx.x * BLK + tid;
    if (b >= B) return;

    // cumulative X_j = T_j ... T_0 ; base-frame twist/accel ; prefix sum U
    float XR[9] = {1.f,0.f,0.f, 0.f,1.f,0.f, 0.f,0.f,1.f};
    float Xp[3] = {0.f, 0.f, 0.f};
    float bv[6] = {0.f, 0.f, 0.f, 0.f, 0.f, 0.f};
    float ba[6] = {0.f, 0.f, 0.f, -gvec[0], -gvec[1], -gvec[2]};
    float U[6]  = {0.f, 0.f, 0.f, 0.f, 0.f, 0.f};

#pragma unroll 1
    for (int j = 0; j < JN; ++j) {
        // ---- uniform constants (scalar loads: address depends only on j) ----
        const float* __restrict__ Am = Alist + j * 6;
        const float* __restrict__ Gm = Glist + j * 36;
        const float* __restrict__ Mj = Mlist + j * 16;
        float Aj[6];
#pragma unroll
        for (int k = 0; k < 6; ++k) Aj[k] = Am[k];

        const float qj   = q[b * JN + j];
        const float dqj  = dq[b * JN + j];
        const float ddqj = ddq[b * JN + j];

        // ---- matrix_exp6(-Aj * qj) ----
        const float w0 = -Aj[0] * qj, w1 = -Aj[1] * qj, w2 = -Aj[2] * qj;
        const float l0 = -Aj[3] * qj, l1 = -Aj[4] * qj, l2 = -Aj[5] * qj;
        const float th = sqrtf(w0*w0 + w1*w1 + w2*w2);
        const bool near = th < 1e-6f;
        const float safe = near ? 1.f : th;
        const float inv = __builtin_amdgcn_rcpf(safe);
        const float x = w0 * inv, y = w1 * inv, z = w2 * inv;
        const float st = __sinf(th), ct = __cosf(th);
        const float s2 = 1.f - ct;
        const float a00 = -(z*z + y*y), a11 = -(z*z + x*x), a22 = -(y*y + x*x);
        const float a01 = x*y, a02 = x*z, a12 = y*z;
        float R[9];
        R[0] = 1.f + s2*a00;     R[1] = -st*z + s2*a01;  R[2] =  st*y + s2*a02;
        R[3] =  st*z + s2*a01;   R[4] = 1.f + s2*a11;    R[5] = -st*x + s2*a12;
        R[6] = -st*y + s2*a02;   R[7] =  st*x + s2*a12;  R[8] = 1.f + s2*a22;
        if (near) {
            R[0]=1.f; R[1]=0.f; R[2]=0.f;
            R[3]=0.f; R[4]=1.f; R[5]=0.f;
            R[6]=0.f; R[7]=0.f; R[8]=1.f;
        }
        const float g3 = th - st;
        const float u0 = l0 * inv, u1 = l1 * inv, u2 = l2 * inv;
        float p0 = th*u0 + s2*(-z*u1 + y*u2) + g3*(a00*u0 + a01*u1 + a02*u2);
        float p1 = th*u1 + s2*( z*u0 - x*u2) + g3*(a01*u0 + a11*u1 + a12*u2);
        float p2 = th*u2 + s2*(-y*u0 + x*u1) + g3*(a02*u0 + a12*u1 + a22*u2);
        if (near) { p0 = l0; p1 = l1; p2 = l2; }

        // ---- T = exp6(-A q) @ inv(M_j):  TR = R @ MrT ; Tp = p - TR @ Mp ----
        // Mr[r][c] = Mj[r*4+c], Mp[c] = Mj[c*4+3]; MrT[t][c] = Mj[c*4+t]
        float TR[9], Tp[3];
        {
#pragma unroll
            for (int r = 0; r < 3; ++r) {
#pragma unroll
                for (int cc = 0; cc < 3; ++cc) {
                    TR[r*3+cc] = R[r*3+0]*Mj[cc*4+0] + R[r*3+1]*Mj[cc*4+1] + R[r*3+2]*Mj[cc*4+2];
                }
            }
            const float mp0 = Mj[3], mp1 = Mj[7], mp2 = Mj[11];
            Tp[0] = p0 - (TR[0]*mp0 + TR[1]*mp1 + TR[2]*mp2);
            Tp[1] = p1 - (TR[3]*mp0 + TR[4]*mp1 + TR[5]*mp2);
            Tp[2] = p2 - (TR[6]*mp0 + TR[7]*mp1 + TR[8]*mp2);
        }

        // ---- X_j = T_j @ X_{j-1} ----
        {
            float nR[9], np[3];
#pragma unroll
            for (int r = 0; r < 3; ++r) {
#pragma unroll
                for (int cc = 0; cc < 3; ++cc) {
                    nR[r*3+cc] = TR[r*3+0]*XR[0*3+cc] + TR[r*3+1]*XR[1*3+cc] + TR[r*3+2]*XR[2*3+cc];
                }
            }
            mat3_vec(TR, Xp, np);
#pragma unroll
            for (int r = 0; r < 9; ++r) XR[r] = nR[r];
            Xp[0] = np[0] + Tp[0]; Xp[1] = np[1] + Tp[1]; Xp[2] = np[2] + Tp[2];
        }

        // ---- B_j = Ad(X_j^{-1}) A_j ;  X^{-1} = (XR^T, -XR^T Xp) ----
        float Bv[6];
        {
            float ip[3];
            mat3T_vec(XR, Xp, ip);
            ip[0] = -ip[0]; ip[1] = -ip[1]; ip[2] = -ip[2];
            float tw[3], tv[3], cr[3];
            mat3T_vec(XR, Aj, tw);
            mat3T_vec(XR, Aj + 3, tv);
            cross3(ip, tw, cr);
            Bv[0] = tw[0]; Bv[1] = tw[1]; Bv[2] = tw[2];
            Bv[3] = cr[0] + tv[0]; Bv[4] = cr[1] + tv[1]; Bv[5] = cr[2] + tv[2];
        }

        // ---- sigma_j = B_j . U_{j-1} (before U update) ----
        float sig = Bv[0]*U[0] + Bv[1]*U[1] + Bv[2]*U[2]
                  + Bv[3]*U[3] + Bv[4]*U[4] + Bv[5]*U[5];

        // ---- base-frame twist/accel updates ----
#pragma unroll
        for (int k = 0; k < 6; ++k) bv[k] += Bv[k] * dqj;
        {
            float t0[3], t1[3], t2[3];
            cross3(bv, Bv, t0);        // w(bv) x B_w
            cross3(bv + 3, Bv, t1);    // v(bv) x B_w
            cross3(bv, Bv + 3, t2);    // w(bv) x B_v
            ba[0] += t0[0]*dqj + Bv[0]*ddqj;
            ba[1] += t0[1]*dqj + Bv[1]*ddqj;
            ba[2] += t0[2]*dqj + Bv[2]*ddqj;
            ba[3] += (t1[0]+t2[0])*dqj + Bv[3]*ddqj;
            ba[4] += (t1[1]+t2[1])*dqj + Bv[4]*ddqj;
            ba[5] += (t1[2]+t2[2])*dqj + Bv[5]*ddqj;
        }

        // ---- link-frame v, a ----
        float vl[6], al[6];
        adj_apply(XR, Xp, bv, vl);
        adj_apply(XR, Xp, ba, al);

        // ---- W_j = G al - ad(vl)^T (G vl) ----
        float Gv[6], Ga[6];
#pragma unroll
        for (int r = 0; r < 6; ++r) {
            float sv = 0.f, sa = 0.f;
#pragma unroll
            for (int kk = 0; kk < 6; ++kk) {
                sv += Gm[r*6+kk] * vl[kk];
                sa += Gm[r*6+kk] * al[kk];
            }
            Gv[r] = sv; Ga[r] = sa;
        }
        float W[6];
        {
            float cw[3], cv[3], cb[3];
            cross3(vl, Gv, cw);          // w x (Gv)_w
            cross3(vl + 3, Gv + 3, cv);  // vv x (Gv)_v
            cross3(vl, Gv + 3, cb);      // w x (Gv)_v
            W[0] = Ga[0]+cw[0]+cv[0]; W[1] = Ga[1]+cw[1]+cv[1]; W[2] = Ga[2]+cw[2]+cv[2];
            W[3] = Ga[3]+cb[0];       W[4] = Ga[4]+cb[1];       W[5] = Ga[5]+cb[2];
        }

        // ---- S_j = Ad(X_j)^T W_j ; U += S_j ----
        {
            float S[6];
            adjT_apply(XR, Xp, W, S);
#pragma unroll
            for (int k = 0; k < 6; ++k) U[k] += S[k];
        }

        // ---- stash B_j, sigma_j (write-once, read in epilogue) ----
#pragma unroll
        for (int k = 0; k < 6; ++k) sB[j * 6 + k][tid] = Bv[k];
        sSig[j][tid] = sig;
    }

    // ---- X_9 = inv(M_9) @ X_8 ; Z = Ad(X_9)^T Ftip ; E = U + Z ----
    float E[6];
    {
        const float* __restrict__ M9 = Mlist + JN * 16;
        // R9 = Mr9^T @ XR ; p9 = Mr9^T (Xp - Mp9)
        float R9[9], p9[3];
#pragma unroll
        for (int r = 0; r < 3; ++r) {
#pragma unroll
            for (int cc = 0; cc < 3; ++cc) {
                R9[r*3+cc] = M9[0*4+r]*XR[0*3+cc] + M9[1*4+r]*XR[1*3+cc] + M9[2*4+r]*XR[2*3+cc];
            }
        }
        float t[3] = { Xp[0] - M9[3], Xp[1] - M9[7], Xp[2] - M9[11] };
        p9[0] = M9[0*4+0]*t[0] + M9[1*4+0]*t[1] + M9[2*4+0]*t[2];
        p9[1] = M9[0*4+1]*t[0] + M9[1*4+1]*t[1] + M9[2*4+1]*t[2];
        p9[2] = M9[0*4+2]*t[0] + M9[1*4+2]*t[1] + M9[2*4+2]*t[2];
        float Ft[6];
#pragma unroll
        for (int k = 0; k < 6; ++k) Ft[k] = Ftip[b * 6 + k];
        float Z[6];
        adjT_apply(R9, p9, Ft, Z);
#pragma unroll
        for (int k = 0; k < 6; ++k) E[k] = U[k] + Z[k];
    }

    // ---- tau_i = B_i . E - sigma_i ----
#pragma unroll
    for (int i = 0; i < JN; ++i) {
        float d = -sSig[i][tid];
#pragma unroll
        for (int k = 0; k < 6; ++k) d += sB[i * 6 + k][tid] * E[k];
        out[b * JN + i] = d;
    }
}

extern "C" void kernel_launch(void* const* d_in, const int* in_sizes, int n_in,
                              void* d_out, int out_size, void* d_ws, size_t ws_size,
                              hipStream_t stream) {
    const float* q     = (const float*)d_in[0];
    const float* dq    = (const float*)d_in[1];
    const float* ddq   = (const float*)d_in[2];
    const float* g     = (const float*)d_in[3];
    const float* Ftip  = (const float*)d_in[4];
    const float* Alist = (const float*)d_in[5];
    const float* Mlist = (const float*)d_in[6];
    const float* Glist = (const float*)d_in[7];
    float* out = (float*)d_out;

    const int B = in_sizes[0] / JN;
    const int grid = (B + BLK - 1) / BLK;
    hipLaunchKernelGGL(id_kernel, dim3(grid), dim3(BLK), 0, stream,
                       q, dq, ddq, g, Ftip, Alist, Mlist, Glist, out, B);
}